// Round 4
// baseline (340.260 us; speedup 1.0000x reference)
//
#include <hip/hip_runtime.h>
#include <math.h>

#define NV 4
#define NB 2
#define NC 32
#define ND 32
#define NH 128
#define NW 160
#define NG 8
#define HW (NH*NW)
#define NPIX (NB*NH*NW)
#define FEATSZ (NV*NB*HW*NC)

#define BOXW 21
#define BOXH 8
#define P4   169          // BOXW*BOXH+1, plane stride in float4

// ---------------------------------------------------------------------------
// proj setup (unchanged)
// ---------------------------------------------------------------------------
__global__ void proj_setup_kernel(const float* __restrict__ proj,
                                  float* __restrict__ pw) {
    int t = blockIdx.x * blockDim.x + threadIdx.x;
    if (t >= NB * NV) return;
    int b = t / NV, v = t % NV;
    const float* Eref = proj + ((b*(NV+1) + 0)*2 + 0)*16;
    const float* Kref = proj + ((b*(NV+1) + 0)*2 + 1)*16;
    const float* Esrc = proj + ((b*(NV+1) + (v+1))*2 + 0)*16;
    const float* Ksrc = proj + ((b*(NV+1) + (v+1))*2 + 1)*16;
    float Mr[12], Ms[12];
    for (int i = 0; i < 3; ++i)
        for (int j = 0; j < 4; ++j) {
            float sr = 0.f, ss = 0.f;
            for (int k = 0; k < 3; ++k) {
                sr += Kref[i*4+k] * Eref[k*4+j];
                ss += Ksrc[i*4+k] * Esrc[k*4+j];
            }
            Mr[i*4+j] = sr; Ms[i*4+j] = ss;
        }
    double A[9], a[3];
    for (int i = 0; i < 3; ++i) {
        for (int j = 0; j < 3; ++j) A[i*3+j] = (double)Mr[i*4+j];
        a[i] = (double)Mr[i*4+3];
    }
    double c00 = A[4]*A[8]-A[5]*A[7];
    double c01 = A[5]*A[6]-A[3]*A[8];
    double c02 = A[3]*A[7]-A[4]*A[6];
    double det = A[0]*c00 + A[1]*c01 + A[2]*c02;
    double id  = 1.0/det;
    double Ai[9];
    Ai[0]=c00*id;                 Ai[1]=(A[2]*A[7]-A[1]*A[8])*id; Ai[2]=(A[1]*A[5]-A[2]*A[4])*id;
    Ai[3]=c01*id;                 Ai[4]=(A[0]*A[8]-A[2]*A[6])*id; Ai[5]=(A[2]*A[3]-A[0]*A[5])*id;
    Ai[6]=c02*id;                 Ai[7]=(A[1]*A[6]-A[0]*A[7])*id; Ai[8]=(A[0]*A[4]-A[1]*A[3])*id;
    double R[9], T[3];
    for (int i = 0; i < 3; ++i)
        for (int j = 0; j < 3; ++j) {
            double s = 0.0;
            for (int k = 0; k < 3; ++k) s += (double)Ms[i*4+k] * Ai[k*3+j];
            R[i*3+j] = s;
        }
    for (int i = 0; i < 3; ++i) {
        double s = (double)Ms[i*4+3];
        for (int k = 0; k < 3; ++k) s -= R[i*3+k]*a[k];
        T[i] = s;
    }
    float* o = pw + (b*NV + v)*12;
    for (int i = 0; i < 9; ++i) o[i]   = (float)R[i];
    for (int i = 0; i < 3; ++i) o[9+i] = (float)T[i];
}

// ---------------------------------------------------------------------------
// LDS-tiled transpose: [vb][c][hw] -> [vb][hw][c] (unchanged)
// ---------------------------------------------------------------------------
__global__ __launch_bounds__(256) void transpose_kernel(
    const float* __restrict__ in, float* __restrict__ out) {
    __shared__ float lds[NC][65];
    int vb = blockIdx.y;
    int hwbase = blockIdx.x * 64;
    int t = threadIdx.x;
    #pragma unroll
    for (int r = 0; r < 8; ++r) {
        int c  = (t >> 6) + r*4;
        int hw = t & 63;
        lds[c][hw] = in[(vb*NC + c)*HW + hwbase + hw];
    }
    __syncthreads();
    #pragma unroll
    for (int r = 0; r < 8; ++r) {
        int c  = t & 31;
        int hw = (t >> 5) + r*8;
        out[((size_t)vb*HW + hwbase + hw)*NC + c] = lds[c][hw];
    }
}

// ---------------------------------------------------------------------------
// Main. Phases:
//  1) geometry for all 4 views (one f64 divide/view), per-lane taps+weights
//  2) 16 interleaved bbox butterflies + ONE barrier for block bbox
//  3) per view: barrier; stage box to LDS; barrier; dot-product math -> s_v,t_v
//  4) 4-way interleaved softmax butterflies; combine; final softmax+argmax
// Reduction trees identical to R1/R3 -> bit-identical FP results.
// ---------------------------------------------------------------------------
__global__ __launch_bounds__(256, 6) void mvs_kernel_t(
    const float* __restrict__ refT,
    const float* __restrict__ srcT,
    const float* __restrict__ depth_hypo,
    const float* __restrict__ w_reg,
    const float* __restrict__ pw,
    float* __restrict__ out)
{
    __shared__ float4 box4[8*P4];
    __shared__ int red[NV][4][4];   // [view][quant: mnx,mxx,mny,mxy][wave]

    int tid = blockIdx.x * 256 + threadIdx.x;
    int d = threadIdx.x & 31;
    int p = tid >> 5;
    int w = p % NW;
    int h = (p / NW) % NH;
    int b = p / (NW*NH);
    float xf = (float)w, yf = (float)h;
    float depth = depth_hypo[((b*ND + d)*NH + h)*NW + w];

    float wr[NG];
    #pragma unroll
    for (int g = 0; g < NG; ++g) wr[g] = w_reg[g];

    // ---------------- phase 1: geometry, all views ----------------
    float w00a[NV], w01a[NV], w10a[NV], w11a[NV];
    int   xc0a[NV], xc1a[NV], yc0a[NV], yc1a[NV];
    #pragma unroll
    for (int v = 0; v < NV; ++v) {
        const float* RT = pw + (b*NV + v)*12;
        double dd  = (double)depth;
        double px_ = ((double)RT[0]*(double)xf + (double)RT[1]*(double)yf + (double)RT[2])*dd + (double)RT[9];
        double py_ = ((double)RT[3]*(double)xf + (double)RT[4]*(double)yf + (double)RT[5])*dd + (double)RT[10];
        double pz_ = ((double)RT[6]*(double)xf + (double)RT[7]*(double)yf + (double)RT[8])*dd + (double)RT[11];
        if (pz_ == 0.0) pz_ = 1e-9;
        double iz  = 1.0 / pz_;
        double pxd = px_*iz, pyd = py_*iz;
        double x0d = floor(pxd), y0d = floor(pyd);
        int x0i = (int)x0d, y0i = (int)y0d;
        int x1i = x0i + 1,  y1i = y0i + 1;
        float wx = (float)(pxd - x0d), wy = (float)(pyd - y0d);
        float vx0 = (x0i >= 0 && x0i < NW) ? 1.f : 0.f;
        float vx1 = (x1i >= 0 && x1i < NW) ? 1.f : 0.f;
        float vy0 = (y0i >= 0 && y0i < NH) ? 1.f : 0.f;
        float vy1 = (y1i >= 0 && y1i < NH) ? 1.f : 0.f;
        w00a[v] = (1.f-wx)*(1.f-wy) * vx0*vy0;
        w01a[v] = wx*(1.f-wy)       * vx1*vy0;
        w10a[v] = (1.f-wx)*wy       * vx0*vy1;
        w11a[v] = wx*wy             * vx1*vy1;
        xc0a[v] = min(max(x0i,0),NW-1); xc1a[v] = min(max(x1i,0),NW-1);
        yc0a[v] = min(max(y0i,0),NH-1); yc1a[v] = min(max(y1i,0),NH-1);
    }

    // ---------------- phase 2: block bbox, one barrier ----------------
    {
        int mnx[NV], mxx[NV], mny[NV], mxy[NV];
        #pragma unroll
        for (int v = 0; v < NV; ++v) {
            mnx[v] = xc0a[v]; mxx[v] = xc1a[v];
            mny[v] = yc0a[v]; mxy[v] = yc1a[v];
        }
        #pragma unroll
        for (int m = 1; m < 64; m <<= 1) {
            #pragma unroll
            for (int v = 0; v < NV; ++v) {
                mnx[v] = min(mnx[v], __shfl_xor(mnx[v], m, 64));
                mxx[v] = max(mxx[v], __shfl_xor(mxx[v], m, 64));
                mny[v] = min(mny[v], __shfl_xor(mny[v], m, 64));
                mxy[v] = max(mxy[v], __shfl_xor(mxy[v], m, 64));
            }
        }
        int wid = threadIdx.x >> 6;
        if ((threadIdx.x & 63) == 0) {
            #pragma unroll
            for (int v = 0; v < NV; ++v) {
                red[v][0][wid] = mnx[v]; red[v][1][wid] = mxx[v];
                red[v][2][wid] = mny[v]; red[v][3][wid] = mxy[v];
            }
        }
    }
    __syncthreads();
    int x0b[NV], y0b[NV], bwv[NV], bhv[NV];
    bool fitv[NV];
    #pragma unroll
    for (int v = 0; v < NV; ++v) {
        int mnx = min(min(red[v][0][0],red[v][0][1]), min(red[v][0][2],red[v][0][3]));
        int mxx = max(max(red[v][1][0],red[v][1][1]), max(red[v][1][2],red[v][1][3]));
        int mny = min(min(red[v][2][0],red[v][2][1]), min(red[v][2][2],red[v][2][3]));
        int mxy = max(max(red[v][3][0],red[v][3][1]), max(red[v][3][2],red[v][3][3]));
        x0b[v] = mnx; y0b[v] = mny;
        bwv[v] = mxx - mnx + 1;
        bhv[v] = mxy - mny + 1;
        fitv[v] = (bwv[v] <= BOXW) && (bhv[v] <= BOXH);
    }

    // ---------------- phase 3: per view stage + math ----------------
    float sv[NV], tv[NV];
    #pragma unroll
    for (int v = 0; v < NV; ++v) {
        int vb = v*NB + b;
        __syncthreads();   // protect box4 from previous view's readers
        if (fitv[v]) {
            const float4* gsrc = (const float4*)(srcT + ((size_t)vb*HW + (size_t)y0b[v]*NW + x0b[v])*NC);
            int bw = bwv[v], bh = bhv[v];
            int rowlen = bw*8;
            for (int yy = 0; yy < bh; ++yy) {
                for (int n = threadIdx.x; n < rowlen; n += 256) {
                    int ii = n >> 3, jj = n & 7;
                    box4[jj*P4 + yy*bw + ii] = gsrc[yy*(NW*8) + n];
                }
            }
        }
        __syncthreads();

        const float4* rr = (const float4*)(refT + ((size_t)vb*HW + h*NW + w)*NC);
        float w00 = w00a[v], w01 = w01a[v], w10 = w10a[v], w11 = w11a[v];
        float s = 0.f, t = 0.f;
        if (fitv[v]) {
            int bw = bwv[v];
            int b00 = (yc0a[v] - y0b[v])*bw + (xc0a[v] - x0b[v]);
            int b01 = b00 + (xc1a[v] - xc0a[v]);
            int b10 = b00 + (yc1a[v] - yc0a[v])*bw;
            int b11 = b10 + (xc1a[v] - xc0a[v]);
            #pragma unroll
            for (int j = 0; j < NG; ++j) {
                float4 a00 = box4[j*P4 + b00];
                float4 a01 = box4[j*P4 + b01];
                float4 a10 = box4[j*P4 + b10];
                float4 a11 = box4[j*P4 + b11];
                float4 rf  = rr[j];
                float acc = 0.f;
                float f0 = w00*a00.x + w01*a01.x + w10*a10.x + w11*a11.x;
                acc += f0*rf.x;
                float f1 = w00*a00.y + w01*a01.y + w10*a10.y + w11*a11.y;
                acc += f1*rf.y;
                float f2 = w00*a00.z + w01*a01.z + w10*a10.z + w11*a11.z;
                acc += f2*rf.z;
                float f3 = w00*a00.w + w01*a01.w + w10*a10.w + w11*a11.w;
                acc += f3*rf.w;
                float cf = 0.25f*acc;
                s += cf;
                t += cf*wr[j];
            }
        } else {
            int i00 = yc0a[v]*NW+xc0a[v], i01 = yc0a[v]*NW+xc1a[v];
            int i10 = yc1a[v]*NW+xc0a[v], i11 = yc1a[v]*NW+xc1a[v];
            const float4* s00 = (const float4*)(srcT + ((size_t)vb*HW + i00)*NC);
            const float4* s01 = (const float4*)(srcT + ((size_t)vb*HW + i01)*NC);
            const float4* s10 = (const float4*)(srcT + ((size_t)vb*HW + i10)*NC);
            const float4* s11 = (const float4*)(srcT + ((size_t)vb*HW + i11)*NC);
            #pragma unroll
            for (int j = 0; j < NG; ++j) {
                float4 a00 = s00[j], a01 = s01[j], a10 = s10[j], a11 = s11[j];
                float4 rf  = rr[j];
                float acc = 0.f;
                float f0 = w00*a00.x + w01*a01.x + w10*a10.x + w11*a11.x;
                acc += f0*rf.x;
                float f1 = w00*a00.y + w01*a01.y + w10*a10.y + w11*a11.y;
                acc += f1*rf.y;
                float f2 = w00*a00.z + w01*a01.z + w10*a10.z + w11*a11.z;
                acc += f2*rf.z;
                float f3 = w00*a00.w + w01*a01.w + w10*a10.w + w11*a11.w;
                acc += f3*rf.w;
                float cf = 0.25f*acc;
                s += cf;
                t += cf*wr[j];
            }
        }
        sv[v] = s; tv[v] = t;
    }

    // ---------------- phase 4: interleaved softmax reduces ----------------
    float mv[NV];
    #pragma unroll
    for (int v = 0; v < NV; ++v) mv[v] = sv[v];
    #pragma unroll
    for (int mask = 1; mask < 32; mask <<= 1) {
        #pragma unroll
        for (int v = 0; v < NV; ++v)
            mv[v] = fmaxf(mv[v], __shfl_xor(mv[v], mask, 32));
    }
    float Zv[NV];
    #pragma unroll
    for (int v = 0; v < NV; ++v) Zv[v] = expf(sv[v] - mv[v]);
    #pragma unroll
    for (int mask = 1; mask < 32; mask <<= 1) {
        #pragma unroll
        for (int v = 0; v < NV; ++v)
            Zv[v] += __shfl_xor(Zv[v], mask, 32);
    }
    float logacc = 0.f;
    float cwsum  = 1e-8f;
    #pragma unroll
    for (int v = 0; v < NV; ++v) {
        float cw = 1.f / Zv[v];
        logacc += cw * tv[v];
        cwsum  += cw;
    }

    float logit = logacc / (cwsum + 1e-7f);
    float m2 = logit;
    #pragma unroll
    for (int mask = 1; mask < 32; mask <<= 1)
        m2 = fmaxf(m2, __shfl_xor(m2, mask, 32));
    float e2 = expf(logit - m2);
    float Z2 = e2;
    #pragma unroll
    for (int mask = 1; mask < 32; mask <<= 1)
        Z2 += __shfl_xor(Z2, mask, 32);
    float aw = e2 / Z2;
    out[NPIX + ((b*ND + d)*NH + h)*NW + w] = aw;

    float bv2 = aw; int bi = d;
    #pragma unroll
    for (int mask = 1; mask < 32; mask <<= 1) {
        float ov = __shfl_xor(bv2, mask, 32);
        int   oi = __shfl_xor(bi, mask, 32);
        if (ov > bv2 || (ov == bv2 && oi < bi)) { bv2 = ov; bi = oi; }
    }
    float dsel = __shfl(depth, bi, 32);
    if (d == 0) out[p] = dsel;
}

// ---------------------------------------------------------------------------
// Fallback whole-kernel (original layout) if ws too small
// ---------------------------------------------------------------------------
__global__ __launch_bounds__(256) void mvs_kernel(
    const float* __restrict__ ref_feats,
    const float* __restrict__ src_feats,
    const float* __restrict__ depth_hypo,
    const float* __restrict__ w_reg,
    const float* __restrict__ pw,
    float* __restrict__ out)
{
    int tid = blockIdx.x * 256 + threadIdx.x;
    int d = threadIdx.x & 31;
    int p = tid >> 5;
    if (p >= NPIX) return;
    int w = p % NW;
    int h = (p / NW) % NH;
    int b = p / (NW*NH);
    float xf = (float)w, yf = (float)h;
    float depth = depth_hypo[((b*ND + d)*NH + h)*NW + w];
    float wr[NG];
    #pragma unroll
    for (int g = 0; g < NG; ++g) wr[g] = w_reg[g];
    float logacc = 0.f;
    float cwsum  = 1e-8f;
    for (int v = 0; v < NV; ++v) {
        const float* RT = pw + (b*NV + v)*12;
        double dd  = (double)depth;
        double px_ = ((double)RT[0]*(double)xf + (double)RT[1]*(double)yf + (double)RT[2])*dd + (double)RT[9];
        double py_ = ((double)RT[3]*(double)xf + (double)RT[4]*(double)yf + (double)RT[5])*dd + (double)RT[10];
        double pz_ = ((double)RT[6]*(double)xf + (double)RT[7]*(double)yf + (double)RT[8])*dd + (double)RT[11];
        if (pz_ == 0.0) pz_ = 1e-9;
        double iz = 1.0/pz_;
        double pxd = px_*iz, pyd = py_*iz;
        double x0d = floor(pxd), y0d = floor(pyd);
        int x0i = (int)x0d, y0i = (int)y0d;
        int x1i = x0i + 1,  y1i = y0i + 1;
        float wx = (float)(pxd - x0d), wy = (float)(pyd - y0d);
        float vx0 = (x0i >= 0 && x0i < NW) ? 1.f : 0.f;
        float vx1 = (x1i >= 0 && x1i < NW) ? 1.f : 0.f;
        float vy0 = (y0i >= 0 && y0i < NH) ? 1.f : 0.f;
        float vy1 = (y1i >= 0 && y1i < NH) ? 1.f : 0.f;
        float w00 = (1.f-wx)*(1.f-wy) * vx0*vy0;
        float w01 = wx*(1.f-wy)       * vx1*vy0;
        float w10 = (1.f-wx)*wy       * vx0*vy1;
        float w11 = wx*wy             * vx1*vy1;
        int xc0 = min(max(x0i,0),NW-1), xc1 = min(max(x1i,0),NW-1);
        int yc0 = min(max(y0i,0),NH-1), yc1 = min(max(y1i,0),NH-1);
        int i00 = yc0*NW+xc0, i01 = yc0*NW+xc1;
        int i10 = yc1*NW+xc0, i11 = yc1*NW+xc1;
        const float* sb = src_feats + ((v*NB + b)*NC)*HW;
        const float* rb = ref_feats + ((v*NB + b)*NC)*HW + h*NW + w;
        float acc[NG];
        #pragma unroll
        for (int g = 0; g < NG; ++g) acc[g] = 0.f;
        #pragma unroll
        for (int c = 0; c < NC; ++c) {
            const float* scp = sb + c*HW;
            float f = w00*scp[i00] + w01*scp[i01] + w10*scp[i10] + w11*scp[i11];
            acc[c>>2] += f * rb[c*HW];
        }
        float s = 0.f, t = 0.f;
        #pragma unroll
        for (int g = 0; g < NG; ++g) {
            float cf = 0.25f*acc[g];
            s += cf;
            t += cf*wr[g];
        }
        float m = s;
        #pragma unroll
        for (int mask = 1; mask < 32; mask <<= 1)
            m = fmaxf(m, __shfl_xor(m, mask, 32));
        float e = expf(s - m);
        float Z = e;
        #pragma unroll
        for (int mask = 1; mask < 32; mask <<= 1)
            Z += __shfl_xor(Z, mask, 32);
        float cw = 1.f / Z;
        logacc += cw * t;
        cwsum  += cw;
    }
    float logit = logacc / (cwsum + 1e-7f);
    float m2 = logit;
    #pragma unroll
    for (int mask = 1; mask < 32; mask <<= 1)
        m2 = fmaxf(m2, __shfl_xor(m2, mask, 32));
    float e2 = expf(logit - m2);
    float Z2 = e2;
    #pragma unroll
    for (int mask = 1; mask < 32; mask <<= 1)
        Z2 += __shfl_xor(Z2, mask, 32);
    float aw = e2 / Z2;
    out[NPIX + ((b*ND + d)*NH + h)*NW + w] = aw;
    float bv = aw; int bi = d;
    #pragma unroll
    for (int mask = 1; mask < 32; mask <<= 1) {
        float ov = __shfl_xor(bv, mask, 32);
        int   oi = __shfl_xor(bi, mask, 32);
        if (ov > bv || (ov == bv && oi < bi)) { bv = ov; bi = oi; }
    }
    float dsel = __shfl(depth, bi, 32);
    if (d == 0) out[p] = dsel;
}

extern "C" void kernel_launch(void* const* d_in, const int* in_sizes, int n_in,
                              void* d_out, int out_size, void* d_ws, size_t ws_size,
                              hipStream_t stream) {
    const float* ref_feats  = (const float*)d_in[0];
    const float* src_feats  = (const float*)d_in[1];
    const float* proj       = (const float*)d_in[2];
    const float* depth_hypo = (const float*)d_in[3];
    const float* w_reg      = (const float*)d_in[4];
    float* out = (float*)d_out;

    size_t need = (size_t)2*FEATSZ*sizeof(float) + 96*sizeof(float);
    if (ws_size >= need) {
        float* srcT = (float*)d_ws;
        float* refT = srcT + FEATSZ;
        float* pw   = refT + FEATSZ;
        hipLaunchKernelGGL(proj_setup_kernel, dim3(1), dim3(64), 0, stream, proj, pw);
        dim3 tg(HW/64, NV*NB);
        hipLaunchKernelGGL(transpose_kernel, tg, dim3(256), 0, stream, src_feats, srcT);
        hipLaunchKernelGGL(transpose_kernel, tg, dim3(256), 0, stream, ref_feats, refT);
        hipLaunchKernelGGL(mvs_kernel_t, dim3((NPIX*ND)/256), dim3(256), 0, stream,
                           refT, srcT, depth_hypo, w_reg, pw, out);
    } else {
        float* pw = (float*)d_ws;
        hipLaunchKernelGGL(proj_setup_kernel, dim3(1), dim3(64), 0, stream, proj, pw);
        hipLaunchKernelGGL(mvs_kernel, dim3((NPIX*ND)/256), dim3(256), 0, stream,
                           ref_feats, src_feats, depth_hypo, w_reg, pw, out);
    }
}

// Round 5
// 175.407 us; speedup vs baseline: 1.9398x; 1.9398x over previous
//
#include <hip/hip_runtime.h>
#include <math.h>

#define NV 4
#define NB 2
#define NC 32
#define ND 32
#define NH 128
#define NW 160
#define NG 8
#define HW (NH*NW)
#define NPIX (NB*NH*NW)
#define FEATSZ (NV*NB*HW*NC)

// ---------------------------------------------------------------------------
// proj setup (unchanged)
// ---------------------------------------------------------------------------
__global__ void proj_setup_kernel(const float* __restrict__ proj,
                                  float* __restrict__ pw) {
    int t = blockIdx.x * blockDim.x + threadIdx.x;
    if (t >= NB * NV) return;
    int b = t / NV, v = t % NV;
    const float* Eref = proj + ((b*(NV+1) + 0)*2 + 0)*16;
    const float* Kref = proj + ((b*(NV+1) + 0)*2 + 1)*16;
    const float* Esrc = proj + ((b*(NV+1) + (v+1))*2 + 0)*16;
    const float* Ksrc = proj + ((b*(NV+1) + (v+1))*2 + 1)*16;
    float Mr[12], Ms[12];
    for (int i = 0; i < 3; ++i)
        for (int j = 0; j < 4; ++j) {
            float sr = 0.f, ss = 0.f;
            for (int k = 0; k < 3; ++k) {
                sr += Kref[i*4+k] * Eref[k*4+j];
                ss += Ksrc[i*4+k] * Esrc[k*4+j];
            }
            Mr[i*4+j] = sr; Ms[i*4+j] = ss;
        }
    double A[9], a[3];
    for (int i = 0; i < 3; ++i) {
        for (int j = 0; j < 3; ++j) A[i*3+j] = (double)Mr[i*4+j];
        a[i] = (double)Mr[i*4+3];
    }
    double c00 = A[4]*A[8]-A[5]*A[7];
    double c01 = A[5]*A[6]-A[3]*A[8];
    double c02 = A[3]*A[7]-A[4]*A[6];
    double det = A[0]*c00 + A[1]*c01 + A[2]*c02;
    double id  = 1.0/det;
    double Ai[9];
    Ai[0]=c00*id;                 Ai[1]=(A[2]*A[7]-A[1]*A[8])*id; Ai[2]=(A[1]*A[5]-A[2]*A[4])*id;
    Ai[3]=c01*id;                 Ai[4]=(A[0]*A[8]-A[2]*A[6])*id; Ai[5]=(A[2]*A[3]-A[0]*A[5])*id;
    Ai[6]=c02*id;                 Ai[7]=(A[1]*A[6]-A[0]*A[7])*id; Ai[8]=(A[0]*A[4]-A[1]*A[3])*id;
    double R[9], T[3];
    for (int i = 0; i < 3; ++i)
        for (int j = 0; j < 3; ++j) {
            double s = 0.0;
            for (int k = 0; k < 3; ++k) s += (double)Ms[i*4+k] * Ai[k*3+j];
            R[i*3+j] = s;
        }
    for (int i = 0; i < 3; ++i) {
        double s = (double)Ms[i*4+3];
        for (int k = 0; k < 3; ++k) s -= R[i*3+k]*a[k];
        T[i] = s;
    }
    float* o = pw + (b*NV + v)*12;
    for (int i = 0; i < 9; ++i) o[i]   = (float)R[i];
    for (int i = 0; i < 3; ++i) o[9+i] = (float)T[i];
}

// ---------------------------------------------------------------------------
// LDS-tiled transpose: [vb][c][hw] -> [vb][hw][c] (unchanged)
// ---------------------------------------------------------------------------
__global__ __launch_bounds__(256) void transpose_kernel(
    const float* __restrict__ in, float* __restrict__ out) {
    __shared__ float lds[NC][65];
    int vb = blockIdx.y;
    int hwbase = blockIdx.x * 64;
    int t = threadIdx.x;
    #pragma unroll
    for (int r = 0; r < 8; ++r) {
        int c  = (t >> 6) + r*4;
        int hw = t & 63;
        lds[c][hw] = in[(vb*NC + c)*HW + hwbase + hw];
    }
    __syncthreads();
    #pragma unroll
    for (int r = 0; r < 8; ++r) {
        int c  = t & 31;
        int hw = (t >> 5) + r*8;
        out[((size_t)vb*HW + hwbase + hw)*NC + c] = lds[c][hw];
    }
}

// ---------------------------------------------------------------------------
// Main: R1 structure (global float4 gathers, NO LDS, NO barriers) with the
// per-view softmax butterflies deferred and interleaved at the end.
// Per-view work (geometry -> gathers -> dot) leaves only sv[v], tv[v]; the
// 8 reduction trees then run with 4-way ILP. All FP orders unchanged.
// ---------------------------------------------------------------------------
__global__ __launch_bounds__(256) void mvs_kernel_t(
    const float* __restrict__ refT,
    const float* __restrict__ srcT,
    const float* __restrict__ depth_hypo,
    const float* __restrict__ w_reg,
    const float* __restrict__ pw,
    float* __restrict__ out)
{
    int tid = blockIdx.x * 256 + threadIdx.x;
    int d = threadIdx.x & 31;
    int p = tid >> 5;
    if (p >= NPIX) return;
    int w = p % NW;
    int h = (p / NW) % NH;
    int b = p / (NW*NH);
    float xf = (float)w, yf = (float)h;
    float depth = depth_hypo[((b*ND + d)*NH + h)*NW + w];

    float wr[NG];
    #pragma unroll
    for (int g = 0; g < NG; ++g) wr[g] = w_reg[g];

    float sv[NV], tv[NV];

    #pragma unroll
    for (int v = 0; v < NV; ++v) {
        const float* RT = pw + (b*NV + v)*12;
        double dd  = (double)depth;
        double px_ = ((double)RT[0]*(double)xf + (double)RT[1]*(double)yf + (double)RT[2])*dd + (double)RT[9];
        double py_ = ((double)RT[3]*(double)xf + (double)RT[4]*(double)yf + (double)RT[5])*dd + (double)RT[10];
        double pz_ = ((double)RT[6]*(double)xf + (double)RT[7]*(double)yf + (double)RT[8])*dd + (double)RT[11];
        if (pz_ == 0.0) pz_ = 1e-9;
        double iz  = 1.0 / pz_;
        double pxd = px_*iz, pyd = py_*iz;
        double x0d = floor(pxd), y0d = floor(pyd);
        int x0i = (int)x0d, y0i = (int)y0d;
        int x1i = x0i + 1,  y1i = y0i + 1;
        float wx = (float)(pxd - x0d), wy = (float)(pyd - y0d);

        float vx0 = (x0i >= 0 && x0i < NW) ? 1.f : 0.f;
        float vx1 = (x1i >= 0 && x1i < NW) ? 1.f : 0.f;
        float vy0 = (y0i >= 0 && y0i < NH) ? 1.f : 0.f;
        float vy1 = (y1i >= 0 && y1i < NH) ? 1.f : 0.f;
        float w00 = (1.f-wx)*(1.f-wy) * vx0*vy0;
        float w01 = wx*(1.f-wy)       * vx1*vy0;
        float w10 = (1.f-wx)*wy       * vx0*vy1;
        float w11 = wx*wy             * vx1*vy1;
        int xc0 = min(max(x0i,0),NW-1), xc1 = min(max(x1i,0),NW-1);
        int yc0 = min(max(y0i,0),NH-1), yc1 = min(max(y1i,0),NH-1);
        int i00 = yc0*NW+xc0, i01 = yc0*NW+xc1;
        int i10 = yc1*NW+xc0, i11 = yc1*NW+xc1;

        int vb = v*NB + b;
        const float4* s00 = (const float4*)(srcT + ((size_t)vb*HW + i00)*NC);
        const float4* s01 = (const float4*)(srcT + ((size_t)vb*HW + i01)*NC);
        const float4* s10 = (const float4*)(srcT + ((size_t)vb*HW + i10)*NC);
        const float4* s11 = (const float4*)(srcT + ((size_t)vb*HW + i11)*NC);
        const float4* rr  = (const float4*)(refT + ((size_t)vb*HW + h*NW+w)*NC);

        float s = 0.f, t = 0.f;
        #pragma unroll
        for (int j = 0; j < NG; ++j) {
            float4 a00 = s00[j], a01 = s01[j], a10 = s10[j], a11 = s11[j];
            float4 rf  = rr[j];
            float acc = 0.f;
            float f0 = w00*a00.x + w01*a01.x + w10*a10.x + w11*a11.x;
            acc += f0*rf.x;
            float f1 = w00*a00.y + w01*a01.y + w10*a10.y + w11*a11.y;
            acc += f1*rf.y;
            float f2 = w00*a00.z + w01*a01.z + w10*a10.z + w11*a11.z;
            acc += f2*rf.z;
            float f3 = w00*a00.w + w01*a01.w + w10*a10.w + w11*a11.w;
            acc += f3*rf.w;
            float cf = 0.25f*acc;
            s += cf;
            t += cf*wr[j];
        }
        sv[v] = s; tv[v] = t;
    }

    // ---- deferred, interleaved per-view softmax reductions (same trees) ----
    float mv[NV];
    #pragma unroll
    for (int v = 0; v < NV; ++v) mv[v] = sv[v];
    #pragma unroll
    for (int mask = 1; mask < 32; mask <<= 1) {
        #pragma unroll
        for (int v = 0; v < NV; ++v)
            mv[v] = fmaxf(mv[v], __shfl_xor(mv[v], mask, 32));
    }
    float Zv[NV];
    #pragma unroll
    for (int v = 0; v < NV; ++v) Zv[v] = expf(sv[v] - mv[v]);
    #pragma unroll
    for (int mask = 1; mask < 32; mask <<= 1) {
        #pragma unroll
        for (int v = 0; v < NV; ++v)
            Zv[v] += __shfl_xor(Zv[v], mask, 32);
    }
    float logacc = 0.f;
    float cwsum  = 1e-8f;
    #pragma unroll
    for (int v = 0; v < NV; ++v) {
        float cw = 1.f / Zv[v];
        logacc += cw * tv[v];
        cwsum  += cw;
    }

    float logit = logacc / (cwsum + 1e-7f);
    float m2 = logit;
    #pragma unroll
    for (int mask = 1; mask < 32; mask <<= 1)
        m2 = fmaxf(m2, __shfl_xor(m2, mask, 32));
    float e2 = expf(logit - m2);
    float Z2 = e2;
    #pragma unroll
    for (int mask = 1; mask < 32; mask <<= 1)
        Z2 += __shfl_xor(Z2, mask, 32);
    float aw = e2 / Z2;
    out[NPIX + ((b*ND + d)*NH + h)*NW + w] = aw;

    float bv2 = aw; int bi = d;
    #pragma unroll
    for (int mask = 1; mask < 32; mask <<= 1) {
        float ov = __shfl_xor(bv2, mask, 32);
        int   oi = __shfl_xor(bi, mask, 32);
        if (ov > bv2 || (ov == bv2 && oi < bi)) { bv2 = ov; bi = oi; }
    }
    float dsel = __shfl(depth, bi, 32);
    if (d == 0) out[p] = dsel;
}

// ---------------------------------------------------------------------------
// Fallback whole-kernel (original layout) if ws too small
// ---------------------------------------------------------------------------
__global__ __launch_bounds__(256) void mvs_kernel(
    const float* __restrict__ ref_feats,
    const float* __restrict__ src_feats,
    const float* __restrict__ depth_hypo,
    const float* __restrict__ w_reg,
    const float* __restrict__ pw,
    float* __restrict__ out)
{
    int tid = blockIdx.x * 256 + threadIdx.x;
    int d = threadIdx.x & 31;
    int p = tid >> 5;
    if (p >= NPIX) return;
    int w = p % NW;
    int h = (p / NW) % NH;
    int b = p / (NW*NH);
    float xf = (float)w, yf = (float)h;
    float depth = depth_hypo[((b*ND + d)*NH + h)*NW + w];
    float wr[NG];
    #pragma unroll
    for (int g = 0; g < NG; ++g) wr[g] = w_reg[g];
    float logacc = 0.f;
    float cwsum  = 1e-8f;
    for (int v = 0; v < NV; ++v) {
        const float* RT = pw + (b*NV + v)*12;
        double dd  = (double)depth;
        double px_ = ((double)RT[0]*(double)xf + (double)RT[1]*(double)yf + (double)RT[2])*dd + (double)RT[9];
        double py_ = ((double)RT[3]*(double)xf + (double)RT[4]*(double)yf + (double)RT[5])*dd + (double)RT[10];
        double pz_ = ((double)RT[6]*(double)xf + (double)RT[7]*(double)yf + (double)RT[8])*dd + (double)RT[11];
        if (pz_ == 0.0) pz_ = 1e-9;
        double iz = 1.0/pz_;
        double pxd = px_*iz, pyd = py_*iz;
        double x0d = floor(pxd), y0d = floor(pyd);
        int x0i = (int)x0d, y0i = (int)y0d;
        int x1i = x0i + 1,  y1i = y0i + 1;
        float wx = (float)(pxd - x0d), wy = (float)(pyd - y0d);
        float vx0 = (x0i >= 0 && x0i < NW) ? 1.f : 0.f;
        float vx1 = (x1i >= 0 && x1i < NW) ? 1.f : 0.f;
        float vy0 = (y0i >= 0 && y0i < NH) ? 1.f : 0.f;
        float vy1 = (y1i >= 0 && y1i < NH) ? 1.f : 0.f;
        float w00 = (1.f-wx)*(1.f-wy) * vx0*vy0;
        float w01 = wx*(1.f-wy)       * vx1*vy0;
        float w10 = (1.f-wx)*wy       * vx0*vy1;
        float w11 = wx*wy             * vx1*vy1;
        int xc0 = min(max(x0i,0),NW-1), xc1 = min(max(x1i,0),NW-1);
        int yc0 = min(max(y0i,0),NH-1), yc1 = min(max(y1i,0),NH-1);
        int i00 = yc0*NW+xc0, i01 = yc0*NW+xc1;
        int i10 = yc1*NW+xc0, i11 = yc1*NW+xc1;
        const float* sb = src_feats + ((v*NB + b)*NC)*HW;
        const float* rb = ref_feats + ((v*NB + b)*NC)*HW + h*NW + w;
        float acc[NG];
        #pragma unroll
        for (int g = 0; g < NG; ++g) acc[g] = 0.f;
        #pragma unroll
        for (int c = 0; c < NC; ++c) {
            const float* scp = sb + c*HW;
            float f = w00*scp[i00] + w01*scp[i01] + w10*scp[i10] + w11*scp[i11];
            acc[c>>2] += f * rb[c*HW];
        }
        float s = 0.f, t = 0.f;
        #pragma unroll
        for (int g = 0; g < NG; ++g) {
            float cf = 0.25f*acc[g];
            s += cf;
            t += cf*wr[g];
        }
        float m = s;
        #pragma unroll
        for (int mask = 1; mask < 32; mask <<= 1)
            m = fmaxf(m, __shfl_xor(m, mask, 32));
        float e = expf(s - m);
        float Z = e;
        #pragma unroll
        for (int mask = 1; mask < 32; mask <<= 1)
            Z += __shfl_xor(Z, mask, 32);
        float cw = 1.f / Z;
        logacc += cw * t;
        cwsum  += cw;
    }
    float logit = logacc / (cwsum + 1e-7f);
    float m2 = logit;
    #pragma unroll
    for (int mask = 1; mask < 32; mask <<= 1)
        m2 = fmaxf(m2, __shfl_xor(m2, mask, 32));
    float e2 = expf(logit - m2);
    float Z2 = e2;
    #pragma unroll
    for (int mask = 1; mask < 32; mask <<= 1)
        Z2 += __shfl_xor(Z2, mask, 32);
    float aw = e2 / Z2;
    out[NPIX + ((b*ND + d)*NH + h)*NW + w] = aw;
    float bv = aw; int bi = d;
    #pragma unroll
    for (int mask = 1; mask < 32; mask <<= 1) {
        float ov = __shfl_xor(bv, mask, 32);
        int   oi = __shfl_xor(bi, mask, 32);
        if (ov > bv || (ov == bv && oi < bi)) { bv = ov; bi = oi; }
    }
    float dsel = __shfl(depth, bi, 32);
    if (d == 0) out[p] = dsel;
}

extern "C" void kernel_launch(void* const* d_in, const int* in_sizes, int n_in,
                              void* d_out, int out_size, void* d_ws, size_t ws_size,
                              hipStream_t stream) {
    const float* ref_feats  = (const float*)d_in[0];
    const float* src_feats  = (const float*)d_in[1];
    const float* proj       = (const float*)d_in[2];
    const float* depth_hypo = (const float*)d_in[3];
    const float* w_reg      = (const float*)d_in[4];
    float* out = (float*)d_out;

    size_t need = (size_t)2*FEATSZ*sizeof(float) + 96*sizeof(float);
    if (ws_size >= need) {
        float* srcT = (float*)d_ws;
        float* refT = srcT + FEATSZ;
        float* pw   = refT + FEATSZ;
        hipLaunchKernelGGL(proj_setup_kernel, dim3(1), dim3(64), 0, stream, proj, pw);
        dim3 tg(HW/64, NV*NB);
        hipLaunchKernelGGL(transpose_kernel, tg, dim3(256), 0, stream, src_feats, srcT);
        hipLaunchKernelGGL(transpose_kernel, tg, dim3(256), 0, stream, ref_feats, refT);
        hipLaunchKernelGGL(mvs_kernel_t, dim3((NPIX*ND)/256), dim3(256), 0, stream,
                           refT, srcT, depth_hypo, w_reg, pw, out);
    } else {
        float* pw = (float*)d_ws;
        hipLaunchKernelGGL(proj_setup_kernel, dim3(1), dim3(64), 0, stream, proj, pw);
        hipLaunchKernelGGL(mvs_kernel, dim3((NPIX*ND)/256), dim3(256), 0, stream,
                           ref_feats, src_feats, depth_hypo, w_reg, pw, out);
    }
}